// Round 6
// baseline (499.057 us; speedup 1.0000x reference)
//
#include <hip/hip_runtime.h>
#include <math.h>

// (B,T,D) = (32, 2048, 512), fp32 in, fp32 out.
constexpr int B = 32;
constexpr int T = 2048;
constexpr int D = 512;

constexpr int C1 = 32;            // K1: chunks over T (1024 blocks)
constexpr int R1 = T / C1;        // 64 rows per K1 block
constexpr int C2 = 64;            // K2: blocks per batch (one partial per block)
constexpr int RW = 8;             // rows per wave in K2 (4 waves -> 32 rows/block)

// ---------------- K1: partial column sums + counter init ----------------
// P1[b][c][d] = sum_{t in chunk c} x[b][t][d]
__global__ __launch_bounds__(256) void colsum_part(const float* __restrict__ x,
                                                   float* __restrict__ P1,
                                                   unsigned int* __restrict__ cnt) {
    const int b = blockIdx.x, c = blockIdx.y;
    if (c == 0 && threadIdx.x == 0) cnt[b] = 0;          // visible to K2 via kernel-boundary flush
    const int d4 = threadIdx.x & 127;      // float4 column
    const int rp = threadIdx.x >> 7;       // row parity
    const float4* xp = (const float4*)x + ((size_t)(b * T + c * R1) * D >> 2)
                       + (size_t)rp * (D / 4) + d4;
    float4 acc = {0.f, 0.f, 0.f, 0.f};
    #pragma unroll 8
    for (int i = 0; i < R1 / 2; ++i) {
        float4 v = xp[(size_t)i * (D / 2)];
        acc.x += v.x; acc.y += v.y; acc.z += v.z; acc.w += v.w;
    }
    __shared__ float4 lds[128];
    if (rp == 1) lds[d4] = acc;
    __syncthreads();
    if (rp == 0) {
        float4 o = lds[d4];
        acc.x += o.x; acc.y += o.y; acc.z += o.z; acc.w += o.w;
        ((float4*)P1)[(size_t)(b * C1 + c) * (D / 4) + d4] = acc;
    }
}

// ---------------- K2: everything else, 2048 blocks, fan-in finish ----------------
__global__ __launch_bounds__(256) void fused_pool(const float* __restrict__ x,
                                                  const float* __restrict__ P1,
                                                  float* __restrict__ Mp,
                                                  float* __restrict__ Sp,
                                                  float* __restrict__ Op,
                                                  unsigned int* __restrict__ cnt,
                                                  float* __restrict__ out) {
    const int b = blockIdx.x, c = blockIdx.y;
    const int tid = threadIdx.x, wid = tid >> 6, lane = tid & 63;

    __shared__ float  s_lds[D];          // 2 KB: the s vector
    __shared__ float  mred[4], sred[4];
    __shared__ float4 Obuf[4][D / 4];    // 8 KB: per-wave scaled O
    __shared__ float  fmerge[C2];
    __shared__ float  misc[2];           // [0]=Mg, [1]=Sg (merge phase)
    __shared__ int    lastflag;

    // --- in-block s-reduce: thread owns cols (2t, 2t+1), sums C1 chunk partials ---
    {
        const float2* pp = (const float2*)(P1 + (size_t)b * C1 * D) + tid;
        float2 acc = {0.f, 0.f};
        #pragma unroll
        for (int k = 0; k < C1; ++k) {
            float2 v = pp[(size_t)k * (D / 2)];
            acc.x += v.x; acc.y += v.y;
        }
        ((float2*)s_lds)[tid] = acc;
    }
    __syncthreads();
    const float4 s0 = ((const float4*)s_lds)[lane * 2];
    const float4 s1 = ((const float4*)s_lds)[lane * 2 + 1];

    // --- per-wave: 8 rows in registers, dots, one pipelined butterfly ---
    const int t0 = c * (4 * RW) + wid * RW;
    const float4* xr = (const float4*)(x + ((size_t)b * T + t0) * D) + lane * 2;
    float4 X0[RW], X1[RW];
    #pragma unroll
    for (int r = 0; r < RW; ++r) { X0[r] = xr[0]; X1[r] = xr[1]; xr += D / 4; }

    float a[RW];
    #pragma unroll
    for (int r = 0; r < RW; ++r) {
        float t;
        t =      X0[r].x * (s0.x - X0[r].x);
        t = fmaf(X0[r].y,  s0.y - X0[r].y, t);
        t = fmaf(X0[r].z,  s0.z - X0[r].z, t);
        t = fmaf(X0[r].w,  s0.w - X0[r].w, t);
        t = fmaf(X1[r].x,  s1.x - X1[r].x, t);
        t = fmaf(X1[r].y,  s1.y - X1[r].y, t);
        t = fmaf(X1[r].z,  s1.z - X1[r].z, t);
        t = fmaf(X1[r].w,  s1.w - X1[r].w, t);
        a[r] = t;
    }
    #pragma unroll
    for (int off = 1; off < 64; off <<= 1) {
        #pragma unroll
        for (int r = 0; r < RW; ++r) a[r] += __shfl_xor(a[r], off, 64);
    }

    float m = fmaxf(fmaxf(fmaxf(a[0], a[1]), fmaxf(a[2], a[3])),
                    fmaxf(fmaxf(a[4], a[5]), fmaxf(a[6], a[7])));
    float e[RW], ssum = 0.f;
    #pragma unroll
    for (int r = 0; r < RW; ++r) { e[r] = __expf(a[r] - m); ssum += e[r]; }

    float4 O0 = {0.f,0.f,0.f,0.f}, O1 = {0.f,0.f,0.f,0.f};
    #pragma unroll
    for (int r = 0; r < RW; ++r) {
        O0.x = fmaf(e[r], X0[r].x, O0.x); O0.y = fmaf(e[r], X0[r].y, O0.y);
        O0.z = fmaf(e[r], X0[r].z, O0.z); O0.w = fmaf(e[r], X0[r].w, O0.w);
        O1.x = fmaf(e[r], X1[r].x, O1.x); O1.y = fmaf(e[r], X1[r].y, O1.y);
        O1.z = fmaf(e[r], X1[r].z, O1.z); O1.w = fmaf(e[r], X1[r].w, O1.w);
    }

    // --- in-block merge of 4 wave-partials -> one block partial ---
    if (lane == 0) { mred[wid] = m; sred[wid] = ssum; }
    __syncthreads();
    const float Mb = fmaxf(fmaxf(mred[0], mred[1]), fmaxf(mred[2], mred[3]));
    const float fw = __expf(m - Mb);                     // wave-uniform
    float4 t0v = {O0.x * fw, O0.y * fw, O0.z * fw, O0.w * fw};
    float4 t1v = {O1.x * fw, O1.y * fw, O1.z * fw, O1.w * fw};
    Obuf[wid][lane * 2]     = t0v;
    Obuf[wid][lane * 2 + 1] = t1v;
    __syncthreads();
    if (tid == 0) {
        float Sb = sred[0] * __expf(mred[0] - Mb) + sred[1] * __expf(mred[1] - Mb)
                 + sred[2] * __expf(mred[2] - Mb) + sred[3] * __expf(mred[3] - Mb);
        Mp[b * C2 + c] = Mb;
        Sp[b * C2 + c] = Sb;
    }
    if (tid < D / 4) {
        float4 v0 = Obuf[0][tid], v1 = Obuf[1][tid], v2 = Obuf[2][tid], v3 = Obuf[3][tid];
        float4 r;
        r.x = (v0.x + v1.x) + (v2.x + v3.x);
        r.y = (v0.y + v1.y) + (v2.y + v3.y);
        r.z = (v0.z + v1.z) + (v2.z + v3.z);
        r.w = (v0.w + v1.w) + (v2.w + v3.w);
        ((float4*)Op)[(size_t)(b * C2 + c) * (D / 4) + tid] = r;
    }

    // --- release partials, fan-in counter; last block of batch b merges ---
    __threadfence();                                     // L2 writeback (agent release)
    __syncthreads();
    if (tid == 0) {
        unsigned int old = __hip_atomic_fetch_add(&cnt[b], 1u,
                              __ATOMIC_ACQ_REL, __HIP_MEMORY_SCOPE_AGENT);
        lastflag = (old == C2 - 1);
    }
    __syncthreads();
    if (!lastflag) return;
    __builtin_amdgcn_fence(__ATOMIC_ACQUIRE, "agent");   // invalidate before reading others' data

    // --- merge batch b's 64 block partials -> out[b] ---
    if (wid == 0) {                                      // lane = partial index (C2 == 64)
        const float Mc = Mp[b * C2 + lane];
        float mm = Mc;
        #pragma unroll
        for (int off = 1; off < 64; off <<= 1) mm = fmaxf(mm, __shfl_xor(mm, off, 64));
        const float fc = __expf(Mc - mm);
        fmerge[lane] = fc;
        float fs = fc * Sp[b * C2 + lane];
        #pragma unroll
        for (int off = 1; off < 64; off <<= 1) fs += __shfl_xor(fs, off, 64);
        if (lane == 0) { misc[0] = mm; misc[1] = fs; }
    }
    __syncthreads();
    const float invS = 1.0f / misc[1];
    if (tid < D / 4) {
        float4 acc = {0.f,0.f,0.f,0.f};
        const float4* op = (const float4*)Op + (size_t)b * C2 * (D / 4) + tid;
        #pragma unroll 4
        for (int cc = 0; cc < C2; ++cc) {
            const float fc = fmerge[cc];
            float4 v = op[(size_t)cc * (D / 4)];
            acc.x = fmaf(fc, v.x, acc.x); acc.y = fmaf(fc, v.y, acc.y);
            acc.z = fmaf(fc, v.z, acc.z); acc.w = fmaf(fc, v.w, acc.w);
        }
        acc.x *= invS; acc.y *= invS; acc.z *= invS; acc.w *= invS;
        ((float4*)out)[(size_t)b * (D / 4) + tid] = acc;
    }
}

extern "C" void kernel_launch(void* const* d_in, const int* in_sizes, int n_in,
                              void* d_out, int out_size, void* d_ws, size_t ws_size,
                              hipStream_t stream) {
    const float* x = (const float*)d_in[0];
    float* out = (float*)d_out;

    float* P1 = (float*)d_ws;                      // B*C1*D   = 2 MB
    float* Mp = P1 + (size_t)B * C1 * D;           // B*C2     = 8 KB
    float* Sp = Mp + (size_t)B * C2;               // B*C2     = 8 KB
    float* Op = Sp + (size_t)B * C2;               // B*C2*D   = 4 MB
    unsigned int* cnt = (unsigned int*)(Op + (size_t)B * C2 * D);  // 128 B

    colsum_part<<<dim3(B, C1), 256, 0, stream>>>(x, P1, cnt);
    fused_pool<<<dim3(B, C2), 256, 0, stream>>>(x, P1, Mp, Sp, Op, cnt, out);
}

// Round 7
// 225.987 us; speedup vs baseline: 2.2083x; 2.2083x over previous
//
#include <hip/hip_runtime.h>
#include <math.h>

// (B,T,D) = (32, 2048, 512), fp32 in, fp32 out.
constexpr int B = 32;
constexpr int T = 2048;
constexpr int D = 512;

constexpr int C1 = 32;            // K1: chunks over T (1024 blocks)
constexpr int R1 = T / C1;        // 64 rows per K1 block
constexpr int C2 = 128;           // K2: blocks per batch (one partial per block)
constexpr int RW = 4;             // rows per wave (4 waves -> 16 rows/block)
constexpr int NPART = C2;         // 128 block-partials per batch

// ---------------- K1: partial column sums ----------------
// P1[b][c][d] = sum_{t in chunk c} x[b][t][d]
__global__ __launch_bounds__(256) void colsum_part(const float* __restrict__ x,
                                                   float* __restrict__ P1) {
    const int b = blockIdx.x, c = blockIdx.y;
    const int d4 = threadIdx.x & 127;      // float4 column
    const int rp = threadIdx.x >> 7;       // row parity
    const float4* xp = (const float4*)x + ((size_t)(b * T + c * R1) * D >> 2)
                       + (size_t)rp * (D / 4) + d4;
    float4 acc = {0.f, 0.f, 0.f, 0.f};
    #pragma unroll 8
    for (int i = 0; i < R1 / 2; ++i) {
        float4 v = xp[(size_t)i * (D / 2)];
        acc.x += v.x; acc.y += v.y; acc.z += v.z; acc.w += v.w;
    }
    __shared__ float4 lds[128];
    if (rp == 1) lds[d4] = acc;
    __syncthreads();
    if (rp == 0) {
        float4 o = lds[d4];
        acc.x += o.x; acc.y += o.y; acc.z += o.z; acc.w += o.w;
        ((float4*)P1)[(size_t)(b * C1 + c) * (D / 4) + d4] = acc;
    }
}

// ---------------- K2: s-reduce + rowdot + softmax-partial + pool + block merge ----
// Grid (B, C2), 256 thr. Each wave: 4 rows held in registers (32 floats -> no
// compiler re-load, unlike RW=8 which showed VGPR=52 and phantom global
// re-reads). One pipelined butterfly (ILP 4). Block merges its 4 wave-partials
// in LDS -> ONE (M,S,O) partial per block. No fences, no atomics.
__global__ __launch_bounds__(256) void fused_pool(const float* __restrict__ x,
                                                  const float* __restrict__ P1,
                                                  float* __restrict__ Mp,
                                                  float* __restrict__ Sp,
                                                  float* __restrict__ Op) {
    const int b = blockIdx.x, c = blockIdx.y;
    const int tid = threadIdx.x, wid = tid >> 6, lane = tid & 63;

    __shared__ float  s_lds[D];          // 2 KB
    __shared__ float  mred[4], sred[4];
    __shared__ float4 Obuf[4][D / 4];    // 8 KB

    // --- in-block s-reduce: thread owns cols (2t,2t+1), sums C1 chunk partials ---
    {
        const float2* pp = (const float2*)(P1 + (size_t)b * C1 * D) + tid;
        float2 acc = {0.f, 0.f};
        #pragma unroll
        for (int k = 0; k < C1; ++k) {
            float2 v = pp[(size_t)k * (D / 2)];
            acc.x += v.x; acc.y += v.y;
        }
        ((float2*)s_lds)[tid] = acc;
    }
    __syncthreads();
    const float4 s0 = ((const float4*)s_lds)[lane * 2];
    const float4 s1 = ((const float4*)s_lds)[lane * 2 + 1];

    // --- per-wave: 4 rows in registers, independent dots, one butterfly ---
    const int t0 = c * (4 * RW) + wid * RW;
    const float4* xr = (const float4*)(x + ((size_t)b * T + t0) * D) + lane * 2;
    float4 X0[RW], X1[RW];
    #pragma unroll
    for (int r = 0; r < RW; ++r) { X0[r] = xr[0]; X1[r] = xr[1]; xr += D / 4; }

    float a[RW];
    #pragma unroll
    for (int r = 0; r < RW; ++r) {
        float t;
        t =      X0[r].x * (s0.x - X0[r].x);
        t = fmaf(X0[r].y,  s0.y - X0[r].y, t);
        t = fmaf(X0[r].z,  s0.z - X0[r].z, t);
        t = fmaf(X0[r].w,  s0.w - X0[r].w, t);
        t = fmaf(X1[r].x,  s1.x - X1[r].x, t);
        t = fmaf(X1[r].y,  s1.y - X1[r].y, t);
        t = fmaf(X1[r].z,  s1.z - X1[r].z, t);
        t = fmaf(X1[r].w,  s1.w - X1[r].w, t);
        a[r] = t;
    }
    #pragma unroll
    for (int off = 1; off < 64; off <<= 1) {
        #pragma unroll
        for (int r = 0; r < RW; ++r) a[r] += __shfl_xor(a[r], off, 64);
    }

    // --- softmax partial over the wave's 4 rows, pool from registers ---
    float m = fmaxf(fmaxf(a[0], a[1]), fmaxf(a[2], a[3]));
    float e[RW], ssum = 0.f;
    #pragma unroll
    for (int r = 0; r < RW; ++r) { e[r] = __expf(a[r] - m); ssum += e[r]; }

    float4 O0 = {0.f,0.f,0.f,0.f}, O1 = {0.f,0.f,0.f,0.f};
    #pragma unroll
    for (int r = 0; r < RW; ++r) {
        O0.x = fmaf(e[r], X0[r].x, O0.x); O0.y = fmaf(e[r], X0[r].y, O0.y);
        O0.z = fmaf(e[r], X0[r].z, O0.z); O0.w = fmaf(e[r], X0[r].w, O0.w);
        O1.x = fmaf(e[r], X1[r].x, O1.x); O1.y = fmaf(e[r], X1[r].y, O1.y);
        O1.z = fmaf(e[r], X1[r].z, O1.z); O1.w = fmaf(e[r], X1[r].w, O1.w);
    }

    // --- in-block merge: 4 wave-partials -> one block partial ---
    if (lane == 0) { mred[wid] = m; sred[wid] = ssum; }
    __syncthreads();
    const float Mb = fmaxf(fmaxf(mred[0], mred[1]), fmaxf(mred[2], mred[3]));
    const float fw = __expf(m - Mb);                 // wave-uniform
    Obuf[wid][lane * 2]     = make_float4(O0.x * fw, O0.y * fw, O0.z * fw, O0.w * fw);
    Obuf[wid][lane * 2 + 1] = make_float4(O1.x * fw, O1.y * fw, O1.z * fw, O1.w * fw);
    __syncthreads();
    if (tid == 0) {
        float Sb = sred[0] * __expf(mred[0] - Mb) + sred[1] * __expf(mred[1] - Mb)
                 + sred[2] * __expf(mred[2] - Mb) + sred[3] * __expf(mred[3] - Mb);
        Mp[b * C2 + c] = Mb;
        Sp[b * C2 + c] = Sb;
    }
    if (tid < D / 4) {
        float4 v0 = Obuf[0][tid], v1 = Obuf[1][tid], v2 = Obuf[2][tid], v3 = Obuf[3][tid];
        float4 r;
        r.x = (v0.x + v1.x) + (v2.x + v3.x);
        r.y = (v0.y + v1.y) + (v2.y + v3.y);
        r.z = (v0.z + v1.z) + (v2.z + v3.z);
        r.w = (v0.w + v1.w) + (v2.w + v3.w);
        ((float4*)Op)[(size_t)(b * C2 + c) * (D / 4) + tid] = r;
    }
}

// ---------------- K3: merge 128 block-partials per batch -> out ----------------
__global__ __launch_bounds__(256) void merge_out(const float* __restrict__ Mp,
                                                 const float* __restrict__ Sp,
                                                 const float* __restrict__ Op,
                                                 float* __restrict__ out) {
    const int b = blockIdx.x;
    const int tid = threadIdx.x, wid = tid >> 6, lane = tid & 63;
    __shared__ float fmerge[NPART];
    __shared__ float red[4];
    __shared__ float misc[1];

    float Mc = -INFINITY, Sc = 0.f;
    if (tid < NPART) { Mc = Mp[b * NPART + tid]; Sc = Sp[b * NPART + tid]; }

    float mm = Mc;
    #pragma unroll
    for (int off = 1; off < 64; off <<= 1) mm = fmaxf(mm, __shfl_xor(mm, off, 64));
    if (lane == 0) red[wid] = mm;
    __syncthreads();
    const float Mg = fmaxf(fmaxf(red[0], red[1]), fmaxf(red[2], red[3]));
    __syncthreads();

    const float f = __expf(Mc - Mg);                  // 0 for tid >= NPART
    if (tid < NPART) fmerge[tid] = f;
    float fs = f * Sc;
    #pragma unroll
    for (int off = 1; off < 64; off <<= 1) fs += __shfl_xor(fs, off, 64);
    if (lane == 0) red[wid] = fs;
    __syncthreads();
    if (tid == 0) misc[0] = 1.0f / (red[0] + red[1] + red[2] + red[3]);
    __syncthreads();
    const float inv = misc[0];

    // thread owns float2 column tid; accumulate over 128 partials (L2-resident)
    float2 acc = {0.f, 0.f};
    const float2* op = (const float2*)Op + (size_t)b * NPART * (D / 2) + tid;
    #pragma unroll 8
    for (int cc = 0; cc < NPART; ++cc) {
        const float fc = fmerge[cc];
        float2 v = op[(size_t)cc * (D / 2)];
        acc.x = fmaf(fc, v.x, acc.x);
        acc.y = fmaf(fc, v.y, acc.y);
    }
    ((float2*)out)[(size_t)b * (D / 2) + tid] = make_float2(acc.x * inv, acc.y * inv);
}

extern "C" void kernel_launch(void* const* d_in, const int* in_sizes, int n_in,
                              void* d_out, int out_size, void* d_ws, size_t ws_size,
                              hipStream_t stream) {
    const float* x = (const float*)d_in[0];
    float* out = (float*)d_out;

    float* P1 = (float*)d_ws;                      // B*C1*D   = 2 MB
    float* Mp = P1 + (size_t)B * C1 * D;           // B*C2     = 16 KB
    float* Sp = Mp + (size_t)B * C2;               // B*C2     = 16 KB
    float* Op = Sp + (size_t)B * C2;               // B*C2*D   = 8 MB

    colsum_part<<<dim3(B, C1), 256, 0, stream>>>(x, P1);
    fused_pool<<<dim3(B, C2), 256, 0, stream>>>(x, P1, Mp, Sp, Op);
    merge_out<<<B, 256, 0, stream>>>(Mp, Sp, Op, out);
}

// Round 8
// 223.921 us; speedup vs baseline: 2.2287x; 1.0092x over previous
//
#include <hip/hip_runtime.h>
#include <math.h>

// (B,T,D) = (32, 2048, 512), fp32 in, fp32 out.
constexpr int B = 32;
constexpr int T = 2048;
constexpr int D = 512;

constexpr int C1 = 32;            // K1: chunks over T (1024 blocks)
constexpr int R1 = T / C1;        // 64 rows per K1 block
constexpr int C2 = 128;           // K2: blocks per batch (one partial per block)
constexpr int RW = 4;             // rows per wave (4 waves -> 16 rows/block)
constexpr int NPART = C2;         // 128 block-partials per batch

// ---------------- K1: partial column sums ----------------
// P1[b][c][d] = sum_{t in chunk c} x[b][t][d]
__global__ __launch_bounds__(256) void colsum_part(const float* __restrict__ x,
                                                   float* __restrict__ P1) {
    const int b = blockIdx.x, c = blockIdx.y;
    const int d4 = threadIdx.x & 127;      // float4 column
    const int rp = threadIdx.x >> 7;       // row parity
    const float4* xp = (const float4*)x + ((size_t)(b * T + c * R1) * D >> 2)
                       + (size_t)rp * (D / 4) + d4;
    float4 acc = {0.f, 0.f, 0.f, 0.f};
    #pragma unroll 8
    for (int i = 0; i < R1 / 2; ++i) {
        float4 v = xp[(size_t)i * (D / 2)];
        acc.x += v.x; acc.y += v.y; acc.z += v.z; acc.w += v.w;
    }
    __shared__ float4 lds[128];
    if (rp == 1) lds[d4] = acc;
    __syncthreads();
    if (rp == 0) {
        float4 o = lds[d4];
        acc.x += o.x; acc.y += o.y; acc.z += o.z; acc.w += o.w;
        ((float4*)P1)[(size_t)(b * C1 + c) * (D / 4) + d4] = acc;
    }
}

// ---------------- K2: x-prefetch + s-reduce + rowdot + softmax-partial + pool ----
// Single change vs R7: the per-wave x row loads are issued FIRST, before the
// s-reduce and its barrier. In R7 they sat after __syncthreads(), which the
// compiler cannot hoist loads across — serializing P1-reduce then x-load-wait.
// Now both memory streams are in flight concurrently.
__global__ __launch_bounds__(256) void fused_pool(const float* __restrict__ x,
                                                  const float* __restrict__ P1,
                                                  float* __restrict__ Mp,
                                                  float* __restrict__ Sp,
                                                  float* __restrict__ Op) {
    const int b = blockIdx.x, c = blockIdx.y;
    const int tid = threadIdx.x, wid = tid >> 6, lane = tid & 63;

    __shared__ float  s_lds[D];          // 2 KB
    __shared__ float  mred[4], sred[4];
    __shared__ float4 Obuf[4][D / 4];    // 8 KB

    // --- Phase 0: issue x loads first (overlap with s-reduce below) ---
    const int t0 = c * (4 * RW) + wid * RW;
    const float4* xr = (const float4*)(x + ((size_t)b * T + t0) * D) + lane * 2;
    float4 X0[RW], X1[RW];
    #pragma unroll
    for (int r = 0; r < RW; ++r) { X0[r] = xr[0]; X1[r] = xr[1]; xr += D / 4; }

    // --- Phase 1: in-block s-reduce: thread owns cols (2t,2t+1) ---
    {
        const float2* pp = (const float2*)(P1 + (size_t)b * C1 * D) + tid;
        float2 acc = {0.f, 0.f};
        #pragma unroll
        for (int k = 0; k < C1; ++k) {
            float2 v = pp[(size_t)k * (D / 2)];
            acc.x += v.x; acc.y += v.y;
        }
        ((float2*)s_lds)[tid] = acc;
    }
    __syncthreads();
    const float4 s0 = ((const float4*)s_lds)[lane * 2];
    const float4 s1 = ((const float4*)s_lds)[lane * 2 + 1];

    // --- Phase 2: independent dots, one pipelined butterfly ---
    float a[RW];
    #pragma unroll
    for (int r = 0; r < RW; ++r) {
        float t;
        t =      X0[r].x * (s0.x - X0[r].x);
        t = fmaf(X0[r].y,  s0.y - X0[r].y, t);
        t = fmaf(X0[r].z,  s0.z - X0[r].z, t);
        t = fmaf(X0[r].w,  s0.w - X0[r].w, t);
        t = fmaf(X1[r].x,  s1.x - X1[r].x, t);
        t = fmaf(X1[r].y,  s1.y - X1[r].y, t);
        t = fmaf(X1[r].z,  s1.z - X1[r].z, t);
        t = fmaf(X1[r].w,  s1.w - X1[r].w, t);
        a[r] = t;
    }
    #pragma unroll
    for (int off = 1; off < 64; off <<= 1) {
        #pragma unroll
        for (int r = 0; r < RW; ++r) a[r] += __shfl_xor(a[r], off, 64);
    }

    // --- Phase 3: softmax partial over the wave's 4 rows, pool from registers ---
    float m = fmaxf(fmaxf(a[0], a[1]), fmaxf(a[2], a[3]));
    float e[RW], ssum = 0.f;
    #pragma unroll
    for (int r = 0; r < RW; ++r) { e[r] = __expf(a[r] - m); ssum += e[r]; }

    float4 O0 = {0.f,0.f,0.f,0.f}, O1 = {0.f,0.f,0.f,0.f};
    #pragma unroll
    for (int r = 0; r < RW; ++r) {
        O0.x = fmaf(e[r], X0[r].x, O0.x); O0.y = fmaf(e[r], X0[r].y, O0.y);
        O0.z = fmaf(e[r], X0[r].z, O0.z); O0.w = fmaf(e[r], X0[r].w, O0.w);
        O1.x = fmaf(e[r], X1[r].x, O1.x); O1.y = fmaf(e[r], X1[r].y, O1.y);
        O1.z = fmaf(e[r], X1[r].z, O1.z); O1.w = fmaf(e[r], X1[r].w, O1.w);
    }

    // --- Phase 4: in-block merge: 4 wave-partials -> one block partial ---
    if (lane == 0) { mred[wid] = m; sred[wid] = ssum; }
    __syncthreads();
    const float Mb = fmaxf(fmaxf(mred[0], mred[1]), fmaxf(mred[2], mred[3]));
    const float fw = __expf(m - Mb);                 // wave-uniform
    Obuf[wid][lane * 2]     = make_float4(O0.x * fw, O0.y * fw, O0.z * fw, O0.w * fw);
    Obuf[wid][lane * 2 + 1] = make_float4(O1.x * fw, O1.y * fw, O1.z * fw, O1.w * fw);
    __syncthreads();
    if (tid == 0) {
        float Sb = sred[0] * __expf(mred[0] - Mb) + sred[1] * __expf(mred[1] - Mb)
                 + sred[2] * __expf(mred[2] - Mb) + sred[3] * __expf(mred[3] - Mb);
        Mp[b * C2 + c] = Mb;
        Sp[b * C2 + c] = Sb;
    }
    if (tid < D / 4) {
        float4 v0 = Obuf[0][tid], v1 = Obuf[1][tid], v2 = Obuf[2][tid], v3 = Obuf[3][tid];
        float4 r;
        r.x = (v0.x + v1.x) + (v2.x + v3.x);
        r.y = (v0.y + v1.y) + (v2.y + v3.y);
        r.z = (v0.z + v1.z) + (v2.z + v3.z);
        r.w = (v0.w + v1.w) + (v2.w + v3.w);
        ((float4*)Op)[(size_t)(b * C2 + c) * (D / 4) + tid] = r;
    }
}

// ---------------- K3: merge 128 block-partials per batch -> out ----------------
__global__ __launch_bounds__(256) void merge_out(const float* __restrict__ Mp,
                                                 const float* __restrict__ Sp,
                                                 const float* __restrict__ Op,
                                                 float* __restrict__ out) {
    const int b = blockIdx.x;
    const int tid = threadIdx.x, wid = tid >> 6, lane = tid & 63;
    __shared__ float fmerge[NPART];
    __shared__ float red[4];
    __shared__ float misc[1];

    float Mc = -INFINITY, Sc = 0.f;
    if (tid < NPART) { Mc = Mp[b * NPART + tid]; Sc = Sp[b * NPART + tid]; }

    float mm = Mc;
    #pragma unroll
    for (int off = 1; off < 64; off <<= 1) mm = fmaxf(mm, __shfl_xor(mm, off, 64));
    if (lane == 0) red[wid] = mm;
    __syncthreads();
    const float Mg = fmaxf(fmaxf(red[0], red[1]), fmaxf(red[2], red[3]));
    __syncthreads();

    const float f = __expf(Mc - Mg);                  // 0 for tid >= NPART
    if (tid < NPART) fmerge[tid] = f;
    float fs = f * Sc;
    #pragma unroll
    for (int off = 1; off < 64; off <<= 1) fs += __shfl_xor(fs, off, 64);
    if (lane == 0) red[wid] = fs;
    __syncthreads();
    if (tid == 0) misc[0] = 1.0f / (red[0] + red[1] + red[2] + red[3]);
    __syncthreads();
    const float inv = misc[0];

    // thread owns float2 column tid; accumulate over 128 partials (L2-resident)
    float2 acc = {0.f, 0.f};
    const float2* op = (const float2*)Op + (size_t)b * NPART * (D / 2) + tid;
    #pragma unroll 8
    for (int cc = 0; cc < NPART; ++cc) {
        const float fc = fmerge[cc];
        float2 v = op[(size_t)cc * (D / 2)];
        acc.x = fmaf(fc, v.x, acc.x);
        acc.y = fmaf(fc, v.y, acc.y);
    }
    ((float2*)out)[(size_t)b * (D / 2) + tid] = make_float2(acc.x * inv, acc.y * inv);
}

extern "C" void kernel_launch(void* const* d_in, const int* in_sizes, int n_in,
                              void* d_out, int out_size, void* d_ws, size_t ws_size,
                              hipStream_t stream) {
    const float* x = (const float*)d_in[0];
    float* out = (float*)d_out;

    float* P1 = (float*)d_ws;                      // B*C1*D   = 2 MB
    float* Mp = P1 + (size_t)B * C1 * D;           // B*C2     = 16 KB
    float* Sp = Mp + (size_t)B * C2;               // B*C2     = 16 KB
    float* Op = Sp + (size_t)B * C2;               // B*C2*D   = 8 MB

    colsum_part<<<dim3(B, C1), 256, 0, stream>>>(x, P1);
    fused_pool<<<dim3(B, C2), 256, 0, stream>>>(x, P1, Mp, Sp, Op);
    merge_out<<<B, 256, 0, stream>>>(Mp, Sp, Op, out);
}